// Round 1
// baseline (222.160 us; speedup 1.0000x reference)
//
#include <hip/hip_runtime.h>
#include <stdint.h>

#define NBINS 1000

// ---- sortable encoding for f32 min/max via uint atomics ----
__device__ __forceinline__ unsigned enc_f32(float f) {
    unsigned b = __float_as_uint(f);
    return (b & 0x80000000u) ? ~b : (b | 0x80000000u);
}
__device__ __forceinline__ float dec_f32(unsigned e) {
    unsigned b = (e & 0x80000000u) ? (e ^ 0x80000000u) : ~e;
    return __uint_as_float(b);
}

__global__ void init_kernel(unsigned* __restrict__ W) {
    W[0] = 0xFFFFFFFFu;  // running min (encoded)
    W[1] = 0u;           // running max (encoded)
}

__global__ void __launch_bounds__(256) minmax_kernel(
        const float* __restrict__ p, const float* __restrict__ t,
        long long n, unsigned* __restrict__ W) {
    long long n4 = n >> 2;
    const float4* p4 = (const float4*)p;
    const float4* t4 = (const float4*)t;
    unsigned emin = 0xFFFFFFFFu, emax = 0u;
    long long idx = (long long)blockIdx.x * blockDim.x + threadIdx.x;
    long long stride = (long long)gridDim.x * blockDim.x;
    for (long long i = idx; i < n4; i += stride) {
        float4 a = p4[i];
        float4 b = t4[i];
        unsigned e;
        e = enc_f32(a.x); emin = min(emin, e); emax = max(emax, e);
        e = enc_f32(a.y); emin = min(emin, e); emax = max(emax, e);
        e = enc_f32(a.z); emin = min(emin, e); emax = max(emax, e);
        e = enc_f32(a.w); emin = min(emin, e); emax = max(emax, e);
        e = enc_f32(b.x); emin = min(emin, e); emax = max(emax, e);
        e = enc_f32(b.y); emin = min(emin, e); emax = max(emax, e);
        e = enc_f32(b.z); emin = min(emin, e); emax = max(emax, e);
        e = enc_f32(b.w); emin = min(emin, e); emax = max(emax, e);
    }
    // scalar tail (n % 4)
    for (long long i = (n4 << 2) + idx; i < n; i += stride) {
        unsigned e;
        e = enc_f32(p[i]); emin = min(emin, e); emax = max(emax, e);
        e = enc_f32(t[i]); emin = min(emin, e); emax = max(emax, e);
    }
    __shared__ unsigned smin[256];
    __shared__ unsigned smax[256];
    int tid = threadIdx.x;
    smin[tid] = emin; smax[tid] = emax;
    __syncthreads();
    for (int s = 128; s > 0; s >>= 1) {
        if (tid < s) {
            smin[tid] = min(smin[tid], smin[tid + s]);
            smax[tid] = max(smax[tid], smax[tid + s]);
        }
        __syncthreads();
    }
    if (tid == 0) {
        atomicMin(&W[0], smin[0]);
        atomicMax(&W[1], smax[0]);
    }
}

// count of v <= x_j  ==  sum_{k<=j} hist[k]  with  hist bin k = ceil((v-lo)/dx)
__device__ __forceinline__ int binof(float v, float lo, float inv_dx) {
    float u = (v - lo) * inv_dx;
    int k = (int)ceilf(u);
    return min(max(k, 0), NBINS - 1);
}

__global__ void __launch_bounds__(512) hist_kernel(
        const float* __restrict__ p, const float* __restrict__ t,
        long long n, const unsigned* __restrict__ W,
        unsigned* __restrict__ partial) {
    __shared__ unsigned hp[NBINS];
    __shared__ unsigned ht[NBINS];
    for (int i = threadIdx.x; i < NBINS; i += blockDim.x) { hp[i] = 0u; ht[i] = 0u; }
    __syncthreads();

    float lo = dec_f32(W[0]);
    float hi = dec_f32(W[1]);
    float inv_dx = (float)(NBINS - 1) / (hi - lo);

    long long n4 = n >> 2;
    const float4* p4 = (const float4*)p;
    const float4* t4 = (const float4*)t;
    long long idx = (long long)blockIdx.x * blockDim.x + threadIdx.x;
    long long stride = (long long)gridDim.x * blockDim.x;
    for (long long i = idx; i < n4; i += stride) {
        float4 a = p4[i];
        float4 b = t4[i];
        atomicAdd(&hp[binof(a.x, lo, inv_dx)], 1u);
        atomicAdd(&hp[binof(a.y, lo, inv_dx)], 1u);
        atomicAdd(&hp[binof(a.z, lo, inv_dx)], 1u);
        atomicAdd(&hp[binof(a.w, lo, inv_dx)], 1u);
        atomicAdd(&ht[binof(b.x, lo, inv_dx)], 1u);
        atomicAdd(&ht[binof(b.y, lo, inv_dx)], 1u);
        atomicAdd(&ht[binof(b.z, lo, inv_dx)], 1u);
        atomicAdd(&ht[binof(b.w, lo, inv_dx)], 1u);
    }
    for (long long i = (n4 << 2) + idx; i < n; i += stride) {
        atomicAdd(&hp[binof(p[i], lo, inv_dx)], 1u);
        atomicAdd(&ht[binof(t[i], lo, inv_dx)], 1u);
    }
    __syncthreads();
    unsigned* row = partial + (size_t)blockIdx.x * (2 * NBINS);
    for (int i = threadIdx.x; i < NBINS; i += blockDim.x) {
        row[i] = hp[i];
        row[NBINS + i] = ht[i];
    }
}

__global__ void __launch_bounds__(256) reduce_kernel(
        const unsigned* __restrict__ partial, unsigned* __restrict__ W, int G) {
    int j = blockIdx.x * blockDim.x + threadIdx.x;
    if (j >= 2 * NBINS) return;
    unsigned s = 0;
    for (int g = 0; g < G; ++g) s += partial[(size_t)g * (2 * NBINS) + j];
    W[2 + j] = s;
}

__global__ void __launch_bounds__(1024) finalize_kernel(
        const unsigned* __restrict__ W, float* __restrict__ out, long long n) {
    __shared__ unsigned s[1024];
    __shared__ float cp[NBINS];
    __shared__ double rd[1024];
    int t = threadIdx.x;

    // inclusive scan of hist_p
    s[t] = (t < NBINS) ? W[2 + t] : 0u;
    __syncthreads();
    for (int off = 1; off < 1024; off <<= 1) {
        unsigned v = (t >= off) ? s[t - off] : 0u;
        __syncthreads();
        s[t] += v;
        __syncthreads();
    }
    if (t < NBINS) cp[t] = (float)s[t];
    __syncthreads();

    // inclusive scan of hist_t
    s[t] = (t < NBINS) ? W[2 + NBINS + t] : 0u;
    __syncthreads();
    for (int off = 1; off < 1024; off <<= 1) {
        unsigned v = (t >= off) ? s[t - off] : 0u;
        __syncthreads();
        s[t] += v;
        __syncthreads();
    }

    double y = 0.0;
    if (t < NBINS) {
        float invn = 1.0f / (float)n;
        float d = cp[t] * invn - (float)s[t] * invn;
        float yy = d * d;
        float w = (t == 0 || t == NBINS - 1) ? 0.5f : 1.0f;
        y = (double)yy * (double)w;
    }
    rd[t] = y;
    __syncthreads();
    for (int sft = 512; sft > 0; sft >>= 1) {
        if (t < sft) rd[t] += rd[t + sft];
        __syncthreads();
    }
    if (t == 0) {
        float lo = dec_f32(W[0]);
        float hi = dec_f32(W[1]);
        double dx = (double)(hi - lo) / (double)(NBINS - 1);
        out[0] = (float)(rd[0] * dx);
    }
}

extern "C" void kernel_launch(void* const* d_in, const int* in_sizes, int n_in,
                              void* d_out, int out_size, void* d_ws, size_t ws_size,
                              hipStream_t stream) {
    const float* p = (const float*)d_in[0];
    const float* t = (const float*)d_in[1];
    float* out = (float*)d_out;
    long long n = (long long)in_sizes[0];

    unsigned* W = (unsigned*)d_ws;
    const size_t HDR = 4096;  // uints reserved for [min,max,hist_p,hist_t]
    size_t avail = ws_size / 4;
    int G = 256;  // hist blocks
    if (avail < HDR + (size_t)G * 2 * NBINS) {
        size_t room = (avail > HDR) ? (avail - HDR) / (2 * NBINS) : 8;
        G = (int)room;
        if (G > 256) G = 256;
        if (G < 8) G = 8;
    }
    unsigned* partial = W + HDR;

    init_kernel<<<1, 1, 0, stream>>>(W);
    minmax_kernel<<<1024, 256, 0, stream>>>(p, t, n, W);
    hist_kernel<<<G, 512, 0, stream>>>(p, t, n, W, partial);
    reduce_kernel<<<(2 * NBINS + 255) / 256, 256, 0, stream>>>(partial, W, G);
    finalize_kernel<<<1, 1024, 0, stream>>>(W, out, n);
}